// Round 4
// baseline (255.722 us; speedup 1.0000x reference)
//
#include <hip/hip_runtime.h>

// LIF scan over T=8. Rounds 1-3 all ~90us / 2.2 TB/s regardless of source-level
// hoisting: the compiler keeps one load in flight per wave for a single
// recurrence chain (Little's law: ~1KB/wave in flight / ~900ns loaded latency
// == 2.2 TB/s). Fix: 4 INDEPENDENT recurrence chains per thread (4 spatial
// sites striped by thread count). The scheduler interleaves independent chains
// naturally -> >=4 loads in flight per wave -> ~4x BW.

#define DECAY  0.25f
#define THRESH 0.5f

__global__ __launch_bounds__(256) void lif_scan_kernel(
    const float4* __restrict__ x, float4* __restrict__ out,
    int n4, int nthreads) {
    const int tid = blockIdx.x * blockDim.x + threadIdx.x;

    // 4 sites per thread, striped so consecutive lanes hit consecutive float4s.
    const size_t i0 = (size_t)tid;
    const size_t i1 = i0 + (size_t)nthreads;
    const size_t i2 = i0 + 2 * (size_t)nthreads;
    const size_t i3 = i0 + 3 * (size_t)nthreads;
    const size_t stride = (size_t)n4;

    float4 m0 = make_float4(0.f,0.f,0.f,0.f), s0 = m0;
    float4 m1 = m0, s1 = m0;
    float4 m2 = m0, s2 = m0;
    float4 m3 = m0, s3 = m0;

#pragma unroll
    for (int t = 0; t < 8; ++t) {
        const size_t off = (size_t)t * stride;
        // 4 independent loads — scheduler clusters these (separate chains).
        const float4 a = x[off + i0];
        const float4 b = x[off + i1];
        const float4 c = x[off + i2];
        const float4 d = x[off + i3];

        m0.x = m0.x * (DECAY * (1.f - s0.x)) + a.x;
        m0.y = m0.y * (DECAY * (1.f - s0.y)) + a.y;
        m0.z = m0.z * (DECAY * (1.f - s0.z)) + a.z;
        m0.w = m0.w * (DECAY * (1.f - s0.w)) + a.w;
        s0.x = (m0.x >= THRESH) ? 1.f : 0.f;
        s0.y = (m0.y >= THRESH) ? 1.f : 0.f;
        s0.z = (m0.z >= THRESH) ? 1.f : 0.f;
        s0.w = (m0.w >= THRESH) ? 1.f : 0.f;

        m1.x = m1.x * (DECAY * (1.f - s1.x)) + b.x;
        m1.y = m1.y * (DECAY * (1.f - s1.y)) + b.y;
        m1.z = m1.z * (DECAY * (1.f - s1.z)) + b.z;
        m1.w = m1.w * (DECAY * (1.f - s1.w)) + b.w;
        s1.x = (m1.x >= THRESH) ? 1.f : 0.f;
        s1.y = (m1.y >= THRESH) ? 1.f : 0.f;
        s1.z = (m1.z >= THRESH) ? 1.f : 0.f;
        s1.w = (m1.w >= THRESH) ? 1.f : 0.f;

        m2.x = m2.x * (DECAY * (1.f - s2.x)) + c.x;
        m2.y = m2.y * (DECAY * (1.f - s2.y)) + c.y;
        m2.z = m2.z * (DECAY * (1.f - s2.z)) + c.z;
        m2.w = m2.w * (DECAY * (1.f - s2.w)) + c.w;
        s2.x = (m2.x >= THRESH) ? 1.f : 0.f;
        s2.y = (m2.y >= THRESH) ? 1.f : 0.f;
        s2.z = (m2.z >= THRESH) ? 1.f : 0.f;
        s2.w = (m2.w >= THRESH) ? 1.f : 0.f;

        m3.x = m3.x * (DECAY * (1.f - s3.x)) + d.x;
        m3.y = m3.y * (DECAY * (1.f - s3.y)) + d.y;
        m3.z = m3.z * (DECAY * (1.f - s3.z)) + d.z;
        m3.w = m3.w * (DECAY * (1.f - s3.w)) + d.w;
        s3.x = (m3.x >= THRESH) ? 1.f : 0.f;
        s3.y = (m3.y >= THRESH) ? 1.f : 0.f;
        s3.z = (m3.z >= THRESH) ? 1.f : 0.f;
        s3.w = (m3.w >= THRESH) ? 1.f : 0.f;

        out[off + i0] = s0;
        out[off + i1] = s1;
        out[off + i2] = s2;
        out[off + i3] = s3;
    }
}

extern "C" void kernel_launch(void* const* d_in, const int* in_sizes, int n_in,
                              void* d_out, int out_size, void* d_ws, size_t ws_size,
                              hipStream_t stream) {
    const float* x = (const float*)d_in[0];
    float* out = (float*)d_out;

    const int total = in_sizes[0];        // 8 * 32 * 128 * 32 * 32 = 33,554,432
    const int T = 8;
    const int n = total / T;              // 4,194,304 sites per timestep
    const int n4 = n / 4;                 // 1,048,576 float4 groups
    const int nthreads = n4 / 4;          // 262,144 threads, 4 sites each

    const int block = 256;
    const int grid = nthreads / block;    // 1024 blocks

    lif_scan_kernel<<<grid, block, 0, stream>>>(
        (const float4*)x, (float4*)out, n4, nthreads);
}

// Round 5
// 238.409 us; speedup vs baseline: 1.0726x; 1.0726x over previous
//
#include <hip/hip_runtime.h>

// LIF scan over T=8, N=4.2M sites. Rounds 1-4 post-mortem: every compiler
// schedule kept (resident waves x in-flight bytes/wave) constant -> 2.2 TB/s.
// The compiler refuses to keep 8 loads of one recurrence chain outstanding
// (sinks them; sched_barrier(0) lost to earlier passes). This round: take
// waitcnt scheduling away from the compiler. 8 global_load_dwordx4 issued as
// volatile inline asm (invisible to the waitcnt-insertion pass), manual
// s_waitcnt vmcnt(7..0) staircase tied to each dest reg via "+v", spikes
// buffered in regs, all 8 stores after the last wait. 8 KB in flight per wave
// at full 4096-block grid.

typedef float v4f __attribute__((ext_vector_type(4)));

#define DECAY  0.25f
#define THRESH 0.5f

#define LIF_STEP(mv, sv, xv)                                   \
    do {                                                       \
        mv[0] = mv[0] * (DECAY * (1.f - sv[0])) + xv[0];       \
        mv[1] = mv[1] * (DECAY * (1.f - sv[1])) + xv[1];       \
        mv[2] = mv[2] * (DECAY * (1.f - sv[2])) + xv[2];       \
        mv[3] = mv[3] * (DECAY * (1.f - sv[3])) + xv[3];       \
        sv[0] = (mv[0] >= THRESH) ? 1.f : 0.f;                 \
        sv[1] = (mv[1] >= THRESH) ? 1.f : 0.f;                 \
        sv[2] = (mv[2] >= THRESH) ? 1.f : 0.f;                 \
        sv[3] = (mv[3] >= THRESH) ? 1.f : 0.f;                 \
    } while (0)

__global__ __launch_bounds__(256) void lif_scan_kernel(
    const float* __restrict__ x, float* __restrict__ out, int n4) {
    const int i = blockIdx.x * blockDim.x + threadIdx.x;
    if (i >= n4) return;

    const size_t elt    = (size_t)i * 4;   // float offset of this thread's float4
    const size_t stride = (size_t)n4 * 4;  // floats per timestep plane

    const float* p0 = x + elt;
    const float* p1 = p0 + stride;
    const float* p2 = p1 + stride;
    const float* p3 = p2 + stride;
    const float* p4 = p3 + stride;
    const float* p5 = p4 + stride;
    const float* p6 = p5 + stride;
    const float* p7 = p6 + stride;

    v4f x0, x1, x2, x3, x4, x5, x6, x7;
    // 8 loads issued back-to-back; volatile asm keeps issue order and hides
    // them from the compiler's automatic s_waitcnt insertion.
    asm volatile("global_load_dwordx4 %0, %1, off" : "=v"(x0) : "v"(p0));
    asm volatile("global_load_dwordx4 %0, %1, off" : "=v"(x1) : "v"(p1));
    asm volatile("global_load_dwordx4 %0, %1, off" : "=v"(x2) : "v"(p2));
    asm volatile("global_load_dwordx4 %0, %1, off" : "=v"(x3) : "v"(p3));
    asm volatile("global_load_dwordx4 %0, %1, off" : "=v"(x4) : "v"(p4));
    asm volatile("global_load_dwordx4 %0, %1, off" : "=v"(x5) : "v"(p5));
    asm volatile("global_load_dwordx4 %0, %1, off" : "=v"(x6) : "v"(p6));
    asm volatile("global_load_dwordx4 %0, %1, off" : "=v"(x7) : "v"(p7));

    v4f m = {0.f, 0.f, 0.f, 0.f};
    v4f s = {0.f, 0.f, 0.f, 0.f};
    v4f s0, s1, s2, s3, s4, s5, s6, s7;

    asm volatile("s_waitcnt vmcnt(7)" : "+v"(x0));
    LIF_STEP(m, s, x0);  s0 = s;
    asm volatile("s_waitcnt vmcnt(6)" : "+v"(x1));
    LIF_STEP(m, s, x1);  s1 = s;
    asm volatile("s_waitcnt vmcnt(5)" : "+v"(x2));
    LIF_STEP(m, s, x2);  s2 = s;
    asm volatile("s_waitcnt vmcnt(4)" : "+v"(x3));
    LIF_STEP(m, s, x3);  s3 = s;
    asm volatile("s_waitcnt vmcnt(3)" : "+v"(x4));
    LIF_STEP(m, s, x4);  s4 = s;
    asm volatile("s_waitcnt vmcnt(2)" : "+v"(x5));
    LIF_STEP(m, s, x5);  s5 = s;
    asm volatile("s_waitcnt vmcnt(1)" : "+v"(x6));
    LIF_STEP(m, s, x6);  s6 = s;
    asm volatile("s_waitcnt vmcnt(0)" : "+v"(x7));
    LIF_STEP(m, s, x7);  s7 = s;

    // All stores after the last wait: they never enter the wait staircase.
    float* q = out + elt;
    *(v4f*)(q + 0 * stride) = s0;
    *(v4f*)(q + 1 * stride) = s1;
    *(v4f*)(q + 2 * stride) = s2;
    *(v4f*)(q + 3 * stride) = s3;
    *(v4f*)(q + 4 * stride) = s4;
    *(v4f*)(q + 5 * stride) = s5;
    *(v4f*)(q + 6 * stride) = s6;
    *(v4f*)(q + 7 * stride) = s7;
}

extern "C" void kernel_launch(void* const* d_in, const int* in_sizes, int n_in,
                              void* d_out, int out_size, void* d_ws, size_t ws_size,
                              hipStream_t stream) {
    const float* x = (const float*)d_in[0];
    float* out = (float*)d_out;

    const int total = in_sizes[0];        // 8 * 32 * 128 * 32 * 32 = 33,554,432
    const int T = 8;
    const int n = total / T;              // 4,194,304 sites per timestep
    const int n4 = n / 4;                 // 1,048,576 float4 groups

    const int block = 256;
    const int grid = (n4 + block - 1) / block;  // 4096 blocks

    lif_scan_kernel<<<grid, block, 0, stream>>>(x, out, n4);
}